// Round 4
// baseline (78.335 us; speedup 1.0000x reference)
//
#include <hip/hip_runtime.h>
#include <math.h>

// B=64, L=65536, widths {10,20,30,40} -> combined 80-tap FIR, d in [-40,39].
// Persistent blocks with register-prefetch double-buffered LDS staging:
// next tile's global loads are issued before the current tile's compute,
// hiding HBM latency even at 1-2 blocks/CU residency.
#define BLOCK 256
#define OPT 8                      // outputs per thread
#define TILE (BLOCK * OPT)         // 2048
#define HALO 48                    // aligned halo (>= 40, multiple of 4)
#define NF 80                      // filter taps
#define LJ 65536                   // row length
#define BATCH 64
#define TPR (LJ / TILE)            // 32 tiles per row
#define NTILES (BATCH * TPR)       // 2048
#define GRID 512                   // persistent blocks; 4 tiles each
#define LDSX4 (TILE / 4 + 2 * HALO / 4)   // 536 logical float4
#define PHYS4(i) ((i) + ((i) >> 3))       // bank-conflict swizzle
#define LDSP4 (LDSX4 + LDSX4 / 8 + 2)     // 605 physical float4
#define R2CNT (LDSX4 - 2 * BLOCK)         // 24 threads stage a 3rd float4

typedef float nfloat4 __attribute__((ext_vector_type(4)));

__device__ __forceinline__ float4 load_guard(const float* __restrict__ x,
                                             long long rb, int j) {
    float4 v;
    if (j >= 0 && j + 3 < LJ) {
        v = *reinterpret_cast<const float4*>(x + rb + j);
    } else {
        v.x = (j + 0 >= 0 && j + 0 < LJ) ? x[rb + j + 0] : 0.0f;
        v.y = (j + 1 >= 0 && j + 1 < LJ) ? x[rb + j + 1] : 0.0f;
        v.z = (j + 2 >= 0 && j + 2 < LJ) ? x[rb + j + 2] : 0.0f;
        v.w = (j + 3 >= 0 && j + 3 < LJ) ? x[rb + j + 3] : 0.0f;
    }
    return v;
}

__global__ __launch_bounds__(BLOCK) void hann_fir_kernel(
    const float* __restrict__ x, const float* __restrict__ tw,
    float* __restrict__ out)
{
    __shared__ float4 xs4[LDSP4];
    __shared__ float Fs[NF];

    const int tid = threadIdx.x;

    // ---- combined filter F into LDS (threads 0..79) ----
    if (tid < NF) {
        float t0 = tw[0], t1 = tw[1], t2 = tw[2], t3 = tw[3];
        float m = fmaxf(fmaxf(t0, t1), fmaxf(t2, t3));
        float e0 = expf(t0 - m), e1 = expf(t1 - m);
        float e2 = expf(t2 - m), e3 = expf(t3 - m);
        float inv = 1.0f / (e0 + e1 + e2 + e3);
        float wts[4] = {e0 * inv, e1 * inv, e2 * inv, e3 * inv};
        float f = 0.0f;
        #pragma unroll
        for (int t = 0; t < 4; ++t) {
            int w = 10 * (t + 1);
            int k = tid - 40 + w;
            if (k >= 0 && k < 2 * w) {
                float h = 0.5f - 0.5f * cosf(6.28318530717958647692f *
                                             (float)k / (float)(2 * w - 1));
                f += wts[t] * h;
            }
        }
        Fs[tid] = f;
    }

    const float4* Fs4 = reinterpret_cast<const float4*>(Fs);
    const int b4 = 2 * tid + (HALO - 40) / 4;  // logical float4 idx of x[j0-40]

    // ---- prologue: prefetch first tile into registers ----
    int tau = blockIdx.x;
    float4 r0, r1, r2;
    {
        int row = tau / TPR, tc = tau - row * TPR;
        long long rb = (long long)row * LJ;
        int ts = tc * TILE - HALO;
        r0 = load_guard(x, rb, ts + 4 * tid);
        r1 = load_guard(x, rb, ts + 4 * (tid + BLOCK));
        if (tid < R2CNT) r2 = load_guard(x, rb, ts + 4 * (tid + 2 * BLOCK));
    }

    while (tau < NTILES) {
        const int row = tau / TPR, tc = tau - row * TPR;
        const long long rb = (long long)row * LJ;
        const int ts = tc * TILE;
        const int tnext = tau + GRID;

        __syncthreads();                 // prev tile's LDS consumers done
        xs4[PHYS4(tid)] = r0;            // implicit vmcnt wait here only
        xs4[PHYS4(tid + BLOCK)] = r1;
        if (tid < R2CNT) xs4[PHYS4(tid + 2 * BLOCK)] = r2;
        __syncthreads();

        // issue next tile's loads NOW; they complete during compute below
        if (tnext < NTILES) {
            int nrow = tnext / TPR, ntc = tnext - nrow * TPR;
            long long nrb = (long long)nrow * LJ;
            int nts = ntc * TILE - HALO;
            r0 = load_guard(x, nrb, nts + 4 * tid);
            r1 = load_guard(x, nrb, nts + 4 * (tid + BLOCK));
            if (tid < R2CNT) r2 = load_guard(x, nrb, nts + 4 * (tid + 2 * BLOCK));
        }

        // ---- FIR: 8 consecutive outputs, rolling 12-float window ----
        float acc[OPT];
        #pragma unroll
        for (int r = 0; r < OPT; ++r) acc[r] = 0.0f;

        float4 c0 = xs4[PHYS4(b4)];
        float4 c1 = xs4[PHYS4(b4 + 1)];
        #pragma unroll
        for (int g = 0; g < NF / 4; ++g) {       // 20 groups of 4 taps
            float4 c2 = xs4[PHYS4(b4 + g + 2)];
            float4 f = Fs4[g];
            float win[12] = {c0.x, c0.y, c0.z, c0.w,
                             c1.x, c1.y, c1.z, c1.w,
                             c2.x, c2.y, c2.z, c2.w};
            #pragma unroll
            for (int r = 0; r < OPT; ++r) {
                acc[r] = fmaf(f.x, win[r + 0], acc[r]);
                acc[r] = fmaf(f.y, win[r + 1], acc[r]);
                acc[r] = fmaf(f.z, win[r + 2], acc[r]);
                acc[r] = fmaf(f.w, win[r + 3], acc[r]);
            }
            c0 = c1; c1 = c2;
        }

        const long long o = rb + ts + OPT * tid;
        nfloat4 o0 = {acc[0], acc[1], acc[2], acc[3]};
        nfloat4 o1 = {acc[4], acc[5], acc[6], acc[7]};
        __builtin_nontemporal_store(o0, reinterpret_cast<nfloat4*>(out + o));
        __builtin_nontemporal_store(o1, reinterpret_cast<nfloat4*>(out + o + 4));

        tau = tnext;
    }
}

extern "C" void kernel_launch(void* const* d_in, const int* in_sizes, int n_in,
                              void* d_out, int out_size, void* d_ws, size_t ws_size,
                              hipStream_t stream) {
    const float* x  = (const float*)d_in[0];   // [64, 65536] fp32
    const float* tw = (const float*)d_in[1];   // [4] fp32
    float* out = (float*)d_out;                // [64, 65536] fp32
    (void)in_sizes; (void)n_in; (void)out_size; (void)d_ws; (void)ws_size;

    hann_fir_kernel<<<dim3(GRID), dim3(BLOCK), 0, stream>>>(x, tw, out);
}

// Round 5
// 76.047 us; speedup vs baseline: 1.0301x; 1.0301x over previous
//
#include <hip/hip_runtime.h>
#include <math.h>

// B=64, L=65536, widths {10,20,30,40} -> combined 80-tap FIR, d in [-40,39].
// Round-3 structure (best measured): one block per 2048-output tile,
// LDS-staged with +1-float4-per-8 swizzle (kills the 16-way bank conflict
// that cost 18 us in Round 1), 8 outputs/thread rolling-window FIR.
// Round-4 persistent/double-buffer variant was neutral-to-worse -> kernel
// is ~5-10 us vs 5.3 us HBM floor; dur_us is dominated by harness fills.
#define BLOCK 256
#define OPT 8                    // outputs per thread
#define TILE (BLOCK * OPT)       // 2048 outputs per block
#define HALO 48                  // aligned left halo (>= 40, multiple of 4)
#define NF 80                    // filter taps
#define LDSX4 (TILE / 4 + 2 * HALO / 4)   // 536 logical float4
#define PHYS4(i) ((i) + ((i) >> 3))       // bank-conflict swizzle
#define LDSP4 (LDSX4 + LDSX4 / 8 + 2)     // 605 physical float4

typedef float nfloat4 __attribute__((ext_vector_type(4)));

__global__ __launch_bounds__(BLOCK) void hann_fir_kernel(
    const float* __restrict__ x, const float* __restrict__ tw,
    float* __restrict__ out, int Ln)
{
    __shared__ float4 xs4[LDSP4];
    __shared__ float Fs[NF];

    const int tid = threadIdx.x;
    const int tiles_per_row = Ln / TILE;
    const int row = blockIdx.x / tiles_per_row;
    const int tile = blockIdx.x - row * tiles_per_row;
    const long long row_base = (long long)row * Ln;
    const int tile_start = tile * TILE;

    // ---- combined filter F into LDS (threads 0..79) ----
    if (tid < NF) {
        float t0 = tw[0], t1 = tw[1], t2 = tw[2], t3 = tw[3];
        float m = fmaxf(fmaxf(t0, t1), fmaxf(t2, t3));
        float e0 = expf(t0 - m), e1 = expf(t1 - m);
        float e2 = expf(t2 - m), e3 = expf(t3 - m);
        float inv = 1.0f / (e0 + e1 + e2 + e3);
        float wts[4] = {e0 * inv, e1 * inv, e2 * inv, e3 * inv};
        float f = 0.0f;
        #pragma unroll
        for (int t = 0; t < 4; ++t) {
            int w = 10 * (t + 1);
            int k = tid - 40 + w;            // hann index for this template
            if (k >= 0 && k < 2 * w) {
                float h = 0.5f - 0.5f * cosf(6.28318530717958647692f *
                                             (float)k / (float)(2 * w - 1));
                f += wts[t] * h;
            }
        }
        Fs[tid] = f;
    }

    // ---- stage x tile + halo into LDS (padded layout), zero at row edges ----
    for (int i4 = tid; i4 < LDSX4; i4 += BLOCK) {
        int j = tile_start - HALO + 4 * i4;   // global col of element 0
        float4 v;
        if (j >= 0 && j + 3 < Ln) {
            v = *reinterpret_cast<const float4*>(x + row_base + j);
        } else {
            v.x = (j + 0 >= 0 && j + 0 < Ln) ? x[row_base + j + 0] : 0.0f;
            v.y = (j + 1 >= 0 && j + 1 < Ln) ? x[row_base + j + 1] : 0.0f;
            v.z = (j + 2 >= 0 && j + 2 < Ln) ? x[row_base + j + 2] : 0.0f;
            v.w = (j + 3 >= 0 && j + 3 < Ln) ? x[row_base + j + 3] : 0.0f;
        }
        xs4[PHYS4(i4)] = v;
    }
    __syncthreads();

    // ---- FIR: 8 consecutive outputs per thread, rolling 12-float window ----
    float acc[OPT];
    #pragma unroll
    for (int r = 0; r < OPT; ++r) acc[r] = 0.0f;

    const float4* Fs4 = reinterpret_cast<const float4*>(Fs);
    const int b4 = 2 * tid + (HALO - 40) / 4;   // logical float4 idx of x[j0-40]

    float4 c0 = xs4[PHYS4(b4)];
    float4 c1 = xs4[PHYS4(b4 + 1)];
    #pragma unroll
    for (int g = 0; g < NF / 4; ++g) {          // 20 groups of 4 taps
        float4 c2 = xs4[PHYS4(b4 + g + 2)];
        float4 f = Fs4[g];
        float win[12] = {c0.x, c0.y, c0.z, c0.w,
                         c1.x, c1.y, c1.z, c1.w,
                         c2.x, c2.y, c2.z, c2.w};
        #pragma unroll
        for (int r = 0; r < OPT; ++r) {
            acc[r] = fmaf(f.x, win[r + 0], acc[r]);
            acc[r] = fmaf(f.y, win[r + 1], acc[r]);
            acc[r] = fmaf(f.z, win[r + 2], acc[r]);
            acc[r] = fmaf(f.w, win[r + 3], acc[r]);
        }
        c0 = c1; c1 = c2;
    }

    // ---- store 8 consecutive outputs as two aligned 16B nontemporal stores ----
    const long long o = row_base + tile_start + OPT * tid;
    nfloat4 o0 = {acc[0], acc[1], acc[2], acc[3]};
    nfloat4 o1 = {acc[4], acc[5], acc[6], acc[7]};
    __builtin_nontemporal_store(o0, reinterpret_cast<nfloat4*>(out + o));
    __builtin_nontemporal_store(o1, reinterpret_cast<nfloat4*>(out + o + 4));
}

extern "C" void kernel_launch(void* const* d_in, const int* in_sizes, int n_in,
                              void* d_out, int out_size, void* d_ws, size_t ws_size,
                              hipStream_t stream) {
    const float* x  = (const float*)d_in[0];   // [64, 65536] fp32
    const float* tw = (const float*)d_in[1];   // [4] fp32
    float* out = (float*)d_out;                // [64, 65536] fp32

    const int B = 64;
    const int L = 65536;
    (void)in_sizes; (void)n_in; (void)out_size; (void)d_ws; (void)ws_size;

    const int tiles_per_row = L / TILE;        // 32
    dim3 grid(B * tiles_per_row);              // 2048 blocks
    dim3 block(BLOCK);
    hann_fir_kernel<<<grid, block, 0, stream>>>(x, tw, out, L);
}